// Round 5
// baseline (298.069 us; speedup 1.0000x reference)
//
#include <hip/hip_runtime.h>
#include <hip/hip_bf16.h>

#define N_NODES 8192
#define E_EDGES 65536
#define HEADS 3
#define CDIM 384
#define NHC 1152
#define T_STEPS 12
#define D_IN 16
#define HID 32
#define PRED_LEN 6
#define OUT_LABEL_OFF 49152   // N_NODES*PRED_LEN elements

#define O_X        0u
#define O_WIH      1572864u
#define O_WHH      1574400u
#define O_BIH      1577472u
#define O_BHH      1577568u
#define O_WGAT     1577664u
#define O_ATTS     2020032u
#define O_ATTD     2021184u
#define O_WEDGE    2022336u
#define O_ATTE     2023488u
#define O_GBIAS    2024640u
#define O_WP1      2025024u
#define O_BP1      2025056u
#define O_WP3      2025057u
#define O_BP3      2025129u
#define O_WC1      2025135u
#define O_BC1      2037423u
#define O_WC2      2037455u
#define O_BC2      2037519u
#define O_EATTR    2037521u
#define CONV_TOTAL 2103057u

#define O_GATIN    2103072u
#define O_GATB     O_GATIN               // bf16 gat_in [N,384]
#define O_WGATB    (O_GATIN + 1572864u)  // bf16 Wgat [1152,384]
#define O_DEG      (O_GATIN + 1794048u)  // int [8192]
#define O_ROWST    (O_GATIN + 1802240u)  // int [8192]
#define O_CURS     (O_GATIN + 1810432u)  // int [8192]
#define O_CSRE     (O_GATIN + 1818624u)  // int [65536]
#define O_HFEAT    5248800u              // bf16 h_feat [N,1152] (4718592 f32 slots)
#define O_GIB      9967392u              // bf16 gi [N,12,96]   (4718592 f32 slots) = O_HFEAT+4718592
#define O_ASRC     14685984u
#define O_ADST     14710560u
#define O_ARAW     14735136u
#define O_WEXP     14931744u
#define O_AMAX     15128352u
#define O_DENOM    15152928u
#define O_GMEAN    15177504u
#define O_POOLED   18323232u
#define O_KH       18326304u
#define O_FLAG     18326307u

typedef __attribute__((ext_vector_type(8))) short short8;
typedef __attribute__((ext_vector_type(4))) float floatx4;

__device__ __forceinline__ float b2f(unsigned short u) {
    return __uint_as_float(((unsigned)u) << 16);
}
__device__ __forceinline__ unsigned short f2b(float f) {
    __hip_bfloat16 b = __float2bfloat16(f);
    return *(unsigned short*)&b;
}
__device__ __forceinline__ unsigned enc_f(float f) {
    unsigned u = __float_as_uint(f);
    return (u & 0x80000000u) ? ~u : (u | 0x80000000u);
}
__device__ __forceinline__ float dec_f(unsigned e) {
    return __uint_as_float((e & 0x80000000u) ? (e & 0x7FFFFFFFu) : ~e);
}

__global__ void detect_kernel(const unsigned short* __restrict__ wih_raw,
                              int* __restrict__ flag)
{
    int lane = threadIdx.x;
    int cnt = 0;
#pragma unroll
    for (int i = 0; i < 8; i++) {
        unsigned short h = wih_raw[(lane * 8 + i) * 2];
        int e = (h >> 7) & 0xFF;
        if (e >= 100 && e <= 127) cnt++;
    }
#pragma unroll
    for (int off = 32; off; off >>= 1) cnt += __shfl_down(cnt, off, 64);
    if (lane == 0) *flag = (cnt >= 300) ? 1 : 0;
}

// converts everything EXCEPT x (gi_kernel reads raw x); indices start at O_WIH
__global__ __launch_bounds__(256) void convert_all(
    const int* __restrict__ flag,
    const void* Wih, const void* Whh, const void* bih, const void* bhh,
    const void* Wgat, const void* atts, const void* attd, const void* Wedge, const void* atte,
    const void* gbias, const void* Wp1, const void* bp1, const void* Wp3, const void* bp3,
    const void* Wc1, const void* bc1, const void* Wc2, const void* bc2, const void* eattr,
    float* __restrict__ dst)
{
    unsigned idx = O_WIH + blockIdx.x * 256 + threadIdx.x;
    if (idx >= CONV_TOTAL) return;
    const void* src; unsigned off;
    if      (idx < O_WHH)   { src = Wih;   off = idx - O_WIH; }
    else if (idx < O_BIH)   { src = Whh;   off = idx - O_WHH; }
    else if (idx < O_BHH)   { src = bih;   off = idx - O_BIH; }
    else if (idx < O_WGAT)  { src = bhh;   off = idx - O_BHH; }
    else if (idx < O_ATTS)  { src = Wgat;  off = idx - O_WGAT; }
    else if (idx < O_ATTD)  { src = atts;  off = idx - O_ATTS; }
    else if (idx < O_WEDGE) { src = attd;  off = idx - O_ATTD; }
    else if (idx < O_ATTE)  { src = Wedge; off = idx - O_WEDGE; }
    else if (idx < O_GBIAS) { src = atte;  off = idx - O_ATTE; }
    else if (idx < O_WP1)   { src = gbias; off = idx - O_GBIAS; }
    else if (idx < O_BP1)   { src = Wp1;   off = idx - O_WP1; }
    else if (idx < O_BP3)   { src = (idx == O_BP1) ? bp1 : Wp3; off = (idx == O_BP1) ? 0 : idx - O_WP3; }
    else if (idx < O_WC1)   { src = bp3;   off = idx - O_BP3; }
    else if (idx < O_BC1)   { src = Wc1;   off = idx - O_WC1; }
    else if (idx < O_WC2)   { src = bc1;   off = idx - O_BC1; }
    else if (idx < O_BC2)   { src = Wc2;   off = idx - O_WC2; }
    else if (idx < O_EATTR) { src = bc2;   off = idx - O_BC2; }
    else                    { src = eattr; off = idx - O_EATTR; }
    float v = (*flag) ? b2f(((const unsigned short*)src)[off])
                      : ((const float*)src)[off];
    dst[idx] = v;
}

__global__ void cvt_wgat(const int* __restrict__ flag,
                         const void* __restrict__ Wg,
                         unsigned short* __restrict__ dstb)
{
    unsigned i = blockIdx.x * 256 + threadIdx.x;
    if (i >= 442368u) return;
    dstb[i] = (*flag) ? ((const unsigned short*)Wg)[i]
                      : f2b(((const float*)Wg)[i]);
}

// ---------------------------------------------------------------- gi = x @ Wih^T + bih
// gi[n][t][96] bf16. Thread per (n,j); reads raw x/Wih/bih with flag branch.
__global__ __launch_bounds__(256) void gi_kernel(
    const int* __restrict__ flag,
    const void* __restrict__ xraw,
    const void* __restrict__ wihraw,
    const void* __restrict__ bihraw,
    unsigned short* __restrict__ gib)
{
    int gid = blockIdx.x * 256 + threadIdx.x;   // N*96
    int n = gid / 96, j = gid - n * 96;
    bool bf = (*flag) != 0;
    float wih[16], bi;
    if (bf) {
        const unsigned short* p = (const unsigned short*)wihraw + j * 16;
#pragma unroll
        for (int i = 0; i < 16; i++) wih[i] = b2f(p[i]);
        bi = b2f(((const unsigned short*)bihraw)[j]);
    } else {
        const float* p = (const float*)wihraw + j * 16;
#pragma unroll
        for (int i = 0; i < 16; i++) wih[i] = p[i];
        bi = ((const float*)bihraw)[j];
    }
    for (int t = 0; t < T_STEPS; t++) {
        float s = bi;
        if (bf) {
            const unsigned short* xp = (const unsigned short*)xraw + (size_t)n * 192 + t * 16;
#pragma unroll
            for (int i = 0; i < 16; i++) s += wih[i] * b2f(xp[i]);
        } else {
            const float* xp = (const float*)xraw + (size_t)n * 192 + t * 16;
#pragma unroll
            for (int i = 0; i < 16; i++) s += wih[i] * xp[i];
        }
        gib[(size_t)n * 1152 + t * 96 + j] = f2b(s);
    }
}

// ---------------------------------------------------------------- GRU (hh recurrence only)
__global__ __launch_bounds__(256) void gru_kernel(
    const unsigned short* __restrict__ gib,
    const float* __restrict__ Whh,
    const float* __restrict__ bhh,
    unsigned short* __restrict__ gat_b)   // [N,384] bf16
{
    __shared__ float hsh[8][32];
    int gid = blockIdx.x * 256 + threadIdx.x;
    int n = gid >> 5;
    int j = gid & 31;
    int wid = threadIdx.x >> 5;

    float whh[3][32], bh[3];
#pragma unroll
    for (int g = 0; g < 3; g++) {
        int row = g * 32 + j;
#pragma unroll
        for (int i = 0; i < 32; i++) whh[g][i] = Whh[row * 32 + i];
        bh[g] = bhh[row];
    }

    float hval = 0.f;
    hsh[wid][j] = 0.f;

    const unsigned short* gp = gib + (size_t)n * 1152 + j;
    unsigned short g0 = gp[0], g1 = gp[32], g2 = gp[64];

    for (int t = 0; t < T_STEPS; t++) {
        float ir = b2f(g0), iz = b2f(g1), inn = b2f(g2);
        if (t < 11) {
            g0 = gp[(t + 1) * 96];
            g1 = gp[(t + 1) * 96 + 32];
            g2 = gp[(t + 1) * 96 + 64];
        }
        float hr = bh[0], hz = bh[1], hn = bh[2];
#pragma unroll
        for (int q = 0; q < 8; q++) {
            float4 hv = *(const float4*)&hsh[wid][q * 4];
            hr += whh[0][q*4+0]*hv.x + whh[0][q*4+1]*hv.y + whh[0][q*4+2]*hv.z + whh[0][q*4+3]*hv.w;
            hz += whh[1][q*4+0]*hv.x + whh[1][q*4+1]*hv.y + whh[1][q*4+2]*hv.z + whh[1][q*4+3]*hv.w;
            hn += whh[2][q*4+0]*hv.x + whh[2][q*4+1]*hv.y + whh[2][q*4+2]*hv.z + whh[2][q*4+3]*hv.w;
        }
        float r = 1.f / (1.f + expf(-(ir + hr)));
        float z = 1.f / (1.f + expf(-(iz + hz)));
        float nn = tanhf(inn + r * hn);
        hval = (1.f - z) * nn + z * hval;

        gat_b[(size_t)n * 384 + t * 32 + j] = f2b(hval);
        hsh[wid][j] = hval;   // wave-synchronous
    }
}

// ---------------------------------------------------------------- MFMA GEMM, bf16 output
__global__ __launch_bounds__(256) void gemm_mfma(
    const unsigned short* __restrict__ Ab,
    const unsigned short* __restrict__ Bb,
    unsigned short* __restrict__ Cb)
{
    __shared__ unsigned short sA[128][40];
    __shared__ unsigned short sB[128][40];
    int tid = threadIdx.x;
    int wave = tid >> 6, lane = tid & 63;
    int wm = (wave >> 1) * 64, wn = (wave & 1) * 64;
    int m0 = blockIdx.x * 128, n0 = blockIdx.y * 128;

    int r0 = tid >> 2;
    int c8 = (tid & 3) * 8;

    floatx4 acc[4][4];
#pragma unroll
    for (int i = 0; i < 4; i++)
#pragma unroll
        for (int j = 0; j < 4; j++) acc[i][j] = 0;

    int ml = lane & 15, kq = (lane >> 4) * 8;

    for (int k0 = 0; k0 < 384; k0 += 32) {
        short8 a0 = *(const short8*)(Ab + (size_t)(m0 + r0) * 384 + k0 + c8);
        short8 a1 = *(const short8*)(Ab + (size_t)(m0 + r0 + 64) * 384 + k0 + c8);
        short8 b0 = *(const short8*)(Bb + (size_t)(n0 + r0) * 384 + k0 + c8);
        short8 b1 = *(const short8*)(Bb + (size_t)(n0 + r0 + 64) * 384 + k0 + c8);

        __syncthreads();
        *(short8*)(&sA[r0][c8])      = a0;
        *(short8*)(&sA[r0 + 64][c8]) = a1;
        *(short8*)(&sB[r0][c8])      = b0;
        *(short8*)(&sB[r0 + 64][c8]) = b1;
        __syncthreads();

        short8 af[4], bf[4];
#pragma unroll
        for (int i = 0; i < 4; i++)
            af[i] = *(const short8*)(&sA[wm + i * 16 + ml][kq]);
#pragma unroll
        for (int j = 0; j < 4; j++)
            bf[j] = *(const short8*)(&sB[wn + j * 16 + ml][kq]);
#pragma unroll
        for (int i = 0; i < 4; i++)
#pragma unroll
            for (int j = 0; j < 4; j++)
                acc[i][j] = __builtin_amdgcn_mfma_f32_16x16x32_bf16(af[i], bf[j], acc[i][j], 0, 0, 0);
    }

    int cn = lane & 15, rq = (lane >> 4) * 4;
#pragma unroll
    for (int i = 0; i < 4; i++)
#pragma unroll
        for (int j = 0; j < 4; j++)
#pragma unroll
            for (int r = 0; r < 4; r++)
                Cb[(size_t)(m0 + wm + i * 16 + rq + r) * NHC + n0 + wn + j * 16 + cn] = f2b(acc[i][j][r]);
}

__global__ __launch_bounds__(256) void att_score_kernel(
    const unsigned short* __restrict__ h_bf,
    const float* __restrict__ att_src,
    const float* __restrict__ att_dst,
    float* __restrict__ a_src, float* __restrict__ a_dst)
{
    int w = (blockIdx.x * 256 + threadIdx.x) >> 6;
    int lane = threadIdx.x & 63;
    int n = w / 3, hd = w % 3;
    const unsigned short* hrow = h_bf + (size_t)n * NHC + hd * CDIM;
    float s0 = 0.f, s1 = 0.f;
#pragma unroll
    for (int q = 0; q < 6; q++) {
        int c = lane + q * 64;
        float hv = b2f(hrow[c]);
        s0 += hv * att_src[hd * CDIM + c];
        s1 += hv * att_dst[hd * CDIM + c];
    }
#pragma unroll
    for (int off = 32; off; off >>= 1) {
        s0 += __shfl_down(s0, off, 64);
        s1 += __shfl_down(s1, off, 64);
    }
    if (lane == 0) { a_src[n * 3 + hd] = s0; a_dst[n * 3 + hd] = s1; }
}

__global__ void edge_const_kernel(const float* __restrict__ Wedge,
                                  const float* __restrict__ att_edge,
                                  float* __restrict__ Kh)
{
    int hd = threadIdx.x >> 6, lane = threadIdx.x & 63;
    float s = 0.f;
#pragma unroll
    for (int q = 0; q < 6; q++) {
        int c = lane + q * 64;
        s += Wedge[hd * CDIM + c] * att_edge[hd * CDIM + c];
    }
#pragma unroll
    for (int off = 32; off; off >>= 1) s += __shfl_down(s, off, 64);
    if (lane == 0) Kh[hd] = s;
}

__global__ __launch_bounds__(256) void edge_score_kernel(
    const int* __restrict__ edge_index,
    const float* __restrict__ edge_attr,
    const float* __restrict__ a_src, const float* __restrict__ a_dst,
    const float* __restrict__ Kh,
    float* __restrict__ a_raw, unsigned* __restrict__ amax_enc,
    int* __restrict__ deg)
{
    int tid = blockIdx.x * 256 + threadIdx.x;
    int hd = tid >> 16;
    int e = tid & (E_EDGES - 1);
    int src = edge_index[e];
    int dst = edge_index[E_EDGES + e];
    float a = a_src[src * 3 + hd] + a_dst[dst * 3 + hd] + edge_attr[e] * Kh[hd];
    a = a > 0.f ? a : 0.2f * a;
    a_raw[hd * E_EDGES + e] = a;
    atomicMax(&amax_enc[dst * 3 + hd], enc_f(a));
    if (hd == 0) atomicAdd(&deg[dst], 1);
}

__global__ __launch_bounds__(256) void scan_kernel(
    const int* __restrict__ deg, int* __restrict__ rowstart, int* __restrict__ cursor)
{
    __shared__ int ps[256];
    int t = threadIdx.x;
    int l[32], s = 0;
#pragma unroll
    for (int i = 0; i < 32; i++) { l[i] = deg[t * 32 + i]; s += l[i]; }
    ps[t] = s;
    __syncthreads();
    if (t == 0) {
        int run = 0;
        for (int i = 0; i < 256; i++) { int v = ps[i]; ps[i] = run; run += v; }
    }
    __syncthreads();
    int b = ps[t];
#pragma unroll
    for (int i = 0; i < 32; i++) {
        rowstart[t * 32 + i] = b;
        cursor[t * 32 + i] = b;
        b += l[i];
    }
}

__global__ __launch_bounds__(256) void edge_exp_kernel(
    const int* __restrict__ edge_index,
    const float* __restrict__ a_raw, const unsigned* __restrict__ amax_enc,
    float* __restrict__ w_exp, float* __restrict__ denom,
    int* __restrict__ cursor, int* __restrict__ csr_e)
{
    int tid = blockIdx.x * 256 + threadIdx.x;
    int hd = tid >> 16;
    int e = tid & (E_EDGES - 1);
    int dst = edge_index[E_EDGES + e];
    float m = dec_f(amax_enc[dst * 3 + hd]);
    float w = expf(a_raw[hd * E_EDGES + e] - m);
    w_exp[hd * E_EDGES + e] = w;
    unsafeAtomicAdd(&denom[dst * 3 + hd], w);
    if (hd == 0) {
        int pos = atomicAdd(&cursor[dst], 1);
        csr_e[pos] = e;
    }
}

// CSR aggregation fused with head-mean+bias, predictor MLP, out_pred write.
__global__ __launch_bounds__(384) void aggregate_fused(
    const int* __restrict__ flag,
    const int* __restrict__ edge_index,
    const unsigned short* __restrict__ h_bf,
    const float* __restrict__ w_exp, const float* __restrict__ denom,
    const int* __restrict__ rowstart, const int* __restrict__ deg,
    const int* __restrict__ csr_e,
    const float* __restrict__ gat_bias,
    const float* __restrict__ Wp1, const float* __restrict__ bp1,
    const float* __restrict__ Wp3, const float* __restrict__ bp3,
    float* __restrict__ gmean,
    void* __restrict__ out_pred)
{
    int dst = blockIdx.x;
    int s = rowstart[dst], d = deg[dst];
    int tid = threadIdx.x;
    const float third = 1.f / 3.f;
    float inv0 = third / (denom[dst * 3 + 0] + 1e-16f);
    float inv1 = third / (denom[dst * 3 + 1] + 1e-16f);
    float inv2 = third / (denom[dst * 3 + 2] + 1e-16f);
    __shared__ int ssrc[64];
    __shared__ float sc0[64], sc1[64], sc2[64];
    __shared__ float gs[384];
    __shared__ float ps[12];
    float a = 0.f;
    for (int ch = 0; ch < d; ch += 64) {
        int m = d - ch; if (m > 64) m = 64;
        __syncthreads();
        if (tid < m) {
            int e = csr_e[s + ch + tid];
            ssrc[tid] = edge_index[e];
            sc0[tid] = w_exp[e] * inv0;
            sc1[tid] = w_exp[E_EDGES + e] * inv1;
            sc2[tid] = w_exp[2 * E_EDGES + e] * inv2;
        }
        __syncthreads();
        for (int i = 0; i < m; i++) {
            const unsigned short* hs = h_bf + (size_t)ssrc[i] * NHC;
            a += sc0[i] * b2f(hs[tid]) + sc1[i] * b2f(hs[tid + CDIM]) + sc2[i] * b2f(hs[tid + 2 * CDIM]);
        }
    }
    float g = a + gat_bias[tid];
    gmean[(size_t)dst * CDIM + tid] = g;
    gs[tid] = g;
    __syncthreads();

    int t = tid >> 5, c = tid & 31;
    float v = gs[t * 32 + c] * Wp1[c];
#pragma unroll
    for (int off = 16; off; off >>= 1) v += __shfl_down(v, off, 32);
    if (c == 0) { float p = v + bp1[0]; ps[t] = p > 0.f ? p : 0.f; }
    __syncthreads();

    if (tid < PRED_LEN) {
        float acc = bp3[tid];
#pragma unroll
        for (int tt = 0; tt < 12; tt++) acc += Wp3[tid * 12 + tt] * ps[tt];
        acc = acc > 0.f ? acc : 0.f;
        size_t oi = (size_t)dst * PRED_LEN + tid;
        if (*flag) ((__hip_bfloat16*)out_pred)[oi] = __float2bfloat16(acc);
        else       ((float*)out_pred)[oi] = acc;
    }
}

__global__ __launch_bounds__(384) void pool_kernel(
    const float* __restrict__ gmean,
    unsigned* __restrict__ pooled_enc)
{
    int b = blockIdx.x, ch = blockIdx.y;
    int tid = threadIdx.x;
    const float* base = gmean + ((size_t)b * 1024 + ch * 64) * CDIM + tid;
    float m = -3.4e38f;
    for (int i = 0; i < 64; i++)
        m = fmaxf(m, base[(size_t)i * CDIM]);
    atomicMax(&pooled_enc[b * CDIM + tid], enc_f(m));
}

// classifier: 8 blocks (one per batch), 384 threads, wave-reduce per output
__global__ __launch_bounds__(384) void cls_kernel(
    const int* __restrict__ flag,
    const unsigned* __restrict__ pooled_enc,
    const float* __restrict__ Wc1, const float* __restrict__ bc1,
    const float* __restrict__ Wc2, const float* __restrict__ bc2,
    void* __restrict__ out_base)
{
    int b = blockIdx.x, t = threadIdx.x;
    __shared__ float l1[32];
    if (t < 32) l1[t] = bc1[t];
    __syncthreads();
    float v = dec_f(pooled_enc[b * CDIM + t]);
#pragma unroll
    for (int i = 0; i < 32; i++) {
        float p = v * Wc1[i * CDIM + t];
#pragma unroll
        for (int off = 32; off; off >>= 1) p += __shfl_down(p, off, 64);
        if ((t & 63) == 0) atomicAdd(&l1[i], p);
    }
    __syncthreads();
    if (t == 0) {
        float l0 = bc2[0], l1v = bc2[1];
#pragma unroll
        for (int ii = 0; ii < 32; ii++) {
            l0  += Wc2[ii] * l1[ii];
            l1v += Wc2[32 + ii] * l1[ii];
        }
        float m = fmaxf(l0, l1v);
        float e0 = expf(l0 - m), e1 = expf(l1v - m);
        float s = e0 + e1;
        if (*flag) {
            __hip_bfloat16* ob = (__hip_bfloat16*)out_base;
            ob[OUT_LABEL_OFF + b * 2 + 0] = __float2bfloat16(e0 / s);
            ob[OUT_LABEL_OFF + b * 2 + 1] = __float2bfloat16(e1 / s);
        } else {
            float* of = (float*)out_base;
            of[OUT_LABEL_OFF + b * 2 + 0] = e0 / s;
            of[OUT_LABEL_OFF + b * 2 + 1] = e1 / s;
        }
    }
}

extern "C" void kernel_launch(void* const* d_in, const int* in_sizes, int n_in,
                              void* d_out, int out_size, void* d_ws, size_t ws_size,
                              hipStream_t stream) {
    float* W = (float*)d_ws;
    int* flag = (int*)(W + O_FLAG);
    const int* edge_index = (const int*)d_in[1];

    size_t zero_floats = (size_t)(O_POOLED + 8 * CDIM) - O_AMAX;
    hipMemsetAsync(W + O_AMAX, 0, zero_floats * 4, stream);
    hipMemsetAsync(W + O_DEG, 0, 8192 * 4, stream);

    detect_kernel<<<1, 64, 0, stream>>>((const unsigned short*)d_in[5], flag);
    convert_all<<<(CONV_TOTAL - O_WIH + 255) / 256, 256, 0, stream>>>(
        flag,
        d_in[5], d_in[6], d_in[7], d_in[8],
        d_in[9], d_in[10], d_in[11], d_in[12], d_in[13],
        d_in[14], d_in[15], d_in[16], d_in[17], d_in[18],
        d_in[19], d_in[20], d_in[21], d_in[22], d_in[2],
        W);
    cvt_wgat<<<(442368 + 255) / 256, 256, 0, stream>>>(
        flag, d_in[9], (unsigned short*)(W + O_WGATB));

    gi_kernel<<<N_NODES * 96 / 256, 256, 0, stream>>>(
        flag, d_in[0], d_in[5], d_in[7], (unsigned short*)(W + O_GIB));
    gru_kernel<<<N_NODES * 32 / 256, 256, 0, stream>>>(
        (const unsigned short*)(W + O_GIB), W + O_WHH, W + O_BHH,
        (unsigned short*)(W + O_GATB));
    gemm_mfma<<<dim3(N_NODES / 128, NHC / 128), 256, 0, stream>>>(
        (const unsigned short*)(W + O_GATB),
        (const unsigned short*)(W + O_WGATB),
        (unsigned short*)(W + O_HFEAT));
    att_score_kernel<<<(N_NODES * 3 * 64) / 256, 256, 0, stream>>>(
        (const unsigned short*)(W + O_HFEAT), W + O_ATTS, W + O_ATTD,
        W + O_ASRC, W + O_ADST);
    edge_const_kernel<<<1, 192, 0, stream>>>(W + O_WEDGE, W + O_ATTE, W + O_KH);
    edge_score_kernel<<<3 * E_EDGES / 256, 256, 0, stream>>>(
        edge_index, W + O_EATTR, W + O_ASRC, W + O_ADST, W + O_KH,
        W + O_ARAW, (unsigned*)(W + O_AMAX), (int*)(W + O_DEG));
    scan_kernel<<<1, 256, 0, stream>>>(
        (const int*)(W + O_DEG), (int*)(W + O_ROWST), (int*)(W + O_CURS));
    edge_exp_kernel<<<3 * E_EDGES / 256, 256, 0, stream>>>(
        edge_index, W + O_ARAW, (const unsigned*)(W + O_AMAX),
        W + O_WEXP, W + O_DENOM, (int*)(W + O_CURS), (int*)(W + O_CSRE));
    aggregate_fused<<<N_NODES, 384, 0, stream>>>(
        flag, edge_index, (const unsigned short*)(W + O_HFEAT),
        W + O_WEXP, W + O_DENOM,
        (const int*)(W + O_ROWST), (const int*)(W + O_DEG),
        (const int*)(W + O_CSRE),
        W + O_GBIAS, W + O_WP1, W + O_BP1, W + O_WP3, W + O_BP3,
        W + O_GMEAN, d_out);
    pool_kernel<<<dim3(8, 16), 384, 0, stream>>>(
        W + O_GMEAN, (unsigned*)(W + O_POOLED));
    cls_kernel<<<8, 384, 0, stream>>>(
        flag, (const unsigned*)(W + O_POOLED),
        W + O_WC1, W + O_BC1, W + O_WC2, W + O_BC2, d_out);
}

// Round 6
// 274.085 us; speedup vs baseline: 1.0875x; 1.0875x over previous
//
#include <hip/hip_runtime.h>
#include <hip/hip_bf16.h>

#define N_NODES 8192
#define E_EDGES 65536
#define HEADS 3
#define CDIM 384
#define NHC 1152
#define T_STEPS 12
#define D_IN 16
#define HID 32
#define PRED_LEN 6
#define OUT_LABEL_OFF 49152   // N_NODES*PRED_LEN elements

#define O_X        0u
#define O_WIH      1572864u
#define O_WHH      1574400u
#define O_BIH      1577472u
#define O_BHH      1577568u
#define O_WGAT     1577664u
#define O_ATTS     2020032u
#define O_ATTD     2021184u
#define O_WEDGE    2022336u
#define O_ATTE     2023488u
#define O_GBIAS    2024640u
#define O_WP1      2025024u
#define O_BP1      2025056u
#define O_WP3      2025057u
#define O_BP3      2025129u
#define O_WC1      2025135u
#define O_BC1      2037423u
#define O_WC2      2037455u
#define O_BC2      2037519u
#define O_EATTR    2037521u
#define CONV_TOTAL 2103057u

#define O_GATIN    2103072u
#define O_GATB     O_GATIN               // bf16 gat_in [N,384]
#define O_WGATB    (O_GATIN + 1572864u)  // bf16 Wgat [1152,384]
#define O_DEG      (O_GATIN + 1794048u)  // int [8192]
#define O_ROWST    (O_GATIN + 1802240u)  // int [8192]
#define O_CURS     (O_GATIN + 1810432u)  // int [8192]
#define O_CSRE     (O_GATIN + 1818624u)  // int [65536]
#define O_HFEAT    5248800u              // bf16 h_feat [N,1152]
#define O_ASRC     14685984u
#define O_ADST     14710560u
#define O_ARAW     14735136u
#define O_WEXP     14931744u
#define O_AMAX     15128352u
#define O_DENOM    15152928u
#define O_GMEAN    15177504u
#define O_POOLED   18323232u
#define O_KH       18326304u
#define O_FLAG     18326307u

typedef __attribute__((ext_vector_type(8))) short short8;
typedef __attribute__((ext_vector_type(4))) float floatx4;

__device__ __forceinline__ float b2f(unsigned short u) {
    return __uint_as_float(((unsigned)u) << 16);
}
__device__ __forceinline__ unsigned short f2b(float f) {
    __hip_bfloat16 b = __float2bfloat16(f);
    return *(unsigned short*)&b;
}
__device__ __forceinline__ unsigned enc_f(float f) {
    unsigned u = __float_as_uint(f);
    return (u & 0x80000000u) ? ~u : (u | 0x80000000u);
}
__device__ __forceinline__ float dec_f(unsigned e) {
    return __uint_as_float((e & 0x80000000u) ? (e & 0x7FFFFFFFu) : ~e);
}

// ------------------------------------------------ fill (zero regions) + dtype detect
// zero total: amax 24576 + denom 24576 + pooled 3072 + deg 8192 = 60416 elems
__global__ __launch_bounds__(256) void fill_detect(
    const unsigned short* __restrict__ wih_raw,
    int* __restrict__ flag,
    float* __restrict__ W)
{
    if (blockIdx.x == 0 && threadIdx.x < 64) {
        int lane = threadIdx.x;
        int cnt = 0;
#pragma unroll
        for (int i = 0; i < 8; i++) {
            unsigned short h = wih_raw[(lane * 8 + i) * 2];
            int e = (h >> 7) & 0xFF;
            if (e >= 100 && e <= 127) cnt++;
        }
#pragma unroll
        for (int off = 32; off; off >>= 1) cnt += __shfl_down(cnt, off, 64);
        if (lane == 0) *flag = (cnt >= 300) ? 1 : 0;
    }
    unsigned idx = blockIdx.x * 256 + threadIdx.x;
    if      (idx < 24576u) W[O_AMAX  + idx] = 0.f;
    else if (idx < 49152u) W[O_DENOM + idx - 24576u] = 0.f;
    else if (idx < 52224u) W[O_POOLED + idx - 49152u] = 0.f;
    else if (idx < 60416u) ((int*)(W + O_DEG))[idx - 52224u] = 0;
}

// ------------------------------------------------ convert all inputs; Wgat branch emits bf16
__global__ __launch_bounds__(256) void convert_all(
    const int* __restrict__ flag,
    const void* x, const void* Wih, const void* Whh, const void* bih, const void* bhh,
    const void* Wgat, const void* atts, const void* attd, const void* Wedge, const void* atte,
    const void* gbias, const void* Wp1, const void* bp1, const void* Wp3, const void* bp3,
    const void* Wc1, const void* bc1, const void* Wc2, const void* bc2, const void* eattr,
    float* __restrict__ dst, unsigned short* __restrict__ wgatb)
{
    unsigned idx = blockIdx.x * 256 + threadIdx.x;
    if (idx >= CONV_TOTAL) return;
    if (idx >= O_WGAT && idx < O_ATTS) {
        unsigned off = idx - O_WGAT;
        wgatb[off] = (*flag) ? ((const unsigned short*)Wgat)[off]
                             : f2b(((const float*)Wgat)[off]);
        return;
    }
    const void* src; unsigned off;
    if      (idx < O_WIH)   { src = x;     off = idx - O_X; }
    else if (idx < O_WHH)   { src = Wih;   off = idx - O_WIH; }
    else if (idx < O_BIH)   { src = Whh;   off = idx - O_WHH; }
    else if (idx < O_BHH)   { src = bih;   off = idx - O_BIH; }
    else if (idx < O_WGAT)  { src = bhh;   off = idx - O_BHH; }
    else if (idx < O_ATTD)  { src = atts;  off = idx - O_ATTS; }
    else if (idx < O_WEDGE) { src = attd;  off = idx - O_ATTD; }
    else if (idx < O_ATTE)  { src = Wedge; off = idx - O_WEDGE; }
    else if (idx < O_GBIAS) { src = atte;  off = idx - O_ATTE; }
    else if (idx < O_WP1)   { src = gbias; off = idx - O_GBIAS; }
    else if (idx < O_BP1)   { src = Wp1;   off = idx - O_WP1; }
    else if (idx < O_BP3)   { src = (idx == O_BP1) ? bp1 : Wp3; off = (idx == O_BP1) ? 0 : idx - O_WP3; }
    else if (idx < O_WC1)   { src = bp3;   off = idx - O_BP3; }
    else if (idx < O_BC1)   { src = Wc1;   off = idx - O_WC1; }
    else if (idx < O_WC2)   { src = bc1;   off = idx - O_BC1; }
    else if (idx < O_BC2)   { src = Wc2;   off = idx - O_WC2; }
    else if (idx < O_EATTR) { src = bc2;   off = idx - O_BC2; }
    else                    { src = eattr; off = idx - O_EATTR; }
    float v = (*flag) ? b2f(((const unsigned short*)src)[off])
                      : ((const float*)src)[off];
    dst[idx] = v;
}

// ------------------------------------------------ fused GRU
// __launch_bounds__(256,2): allow up to 256 VGPRs so wih(48)+whh(96)+state all
// stay register-resident (124-VGPR cap at (256,4) forced per-step spills — R4 evidence).
__global__ __launch_bounds__(256, 2) void gru_kernel(
    const float* __restrict__ xf,
    const float* __restrict__ Wih,
    const float* __restrict__ Whh,
    const float* __restrict__ bih,
    const float* __restrict__ bhh,
    unsigned short* __restrict__ gat_b)   // [N,384] bf16
{
    __shared__ float hsh[8][32];
    int gid = blockIdx.x * 256 + threadIdx.x;
    int n = gid >> 5;
    int j = gid & 31;
    int wid = threadIdx.x >> 5;

    float wih[3][16], whh[3][32], bi[3], bh[3];
#pragma unroll
    for (int g = 0; g < 3; g++) {
        int row = g * 32 + j;
#pragma unroll
        for (int i = 0; i < 16; i++) wih[g][i] = Wih[row * 16 + i];
#pragma unroll
        for (int i = 0; i < 32; i++) whh[g][i] = Whh[row * 32 + i];
        bi[g] = bih[row];
        bh[g] = bhh[row];
    }

    float hval = 0.f;
    hsh[wid][j] = 0.f;

    const float4* x4 = (const float4*)(xf + (size_t)n * 192);

    for (int t = 0; t < T_STEPS; t++) {
        float xv[16];
#pragma unroll
        for (int q = 0; q < 4; q++) {
            float4 p = x4[t * 4 + q];
            xv[q * 4 + 0] = p.x; xv[q * 4 + 1] = p.y;
            xv[q * 4 + 2] = p.z; xv[q * 4 + 3] = p.w;
        }

        float ir = bi[0], iz = bi[1], inn = bi[2];
#pragma unroll
        for (int i = 0; i < 16; i++) {
            ir  += wih[0][i] * xv[i];
            iz  += wih[1][i] * xv[i];
            inn += wih[2][i] * xv[i];
        }
        float hr = bh[0], hz = bh[1], hn = bh[2];
#pragma unroll
        for (int q = 0; q < 8; q++) {
            float4 hv = *(const float4*)&hsh[wid][q * 4];
            hr += whh[0][q*4+0]*hv.x + whh[0][q*4+1]*hv.y + whh[0][q*4+2]*hv.z + whh[0][q*4+3]*hv.w;
            hz += whh[1][q*4+0]*hv.x + whh[1][q*4+1]*hv.y + whh[1][q*4+2]*hv.z + whh[1][q*4+3]*hv.w;
            hn += whh[2][q*4+0]*hv.x + whh[2][q*4+1]*hv.y + whh[2][q*4+2]*hv.z + whh[2][q*4+3]*hv.w;
        }
        float r = 1.f / (1.f + expf(-(ir + hr)));
        float z = 1.f / (1.f + expf(-(iz + hz)));
        float nn = tanhf(inn + r * hn);
        hval = (1.f - z) * nn + z * hval;

        gat_b[(size_t)n * 384 + t * 32 + j] = f2b(hval);
        hsh[wid][j] = hval;   // wave-synchronous (both 32-groups live in one wave)
    }
}

// ------------------------------------------------ MFMA GEMM, bf16 output
__global__ __launch_bounds__(256) void gemm_mfma(
    const unsigned short* __restrict__ Ab,
    const unsigned short* __restrict__ Bb,
    unsigned short* __restrict__ Cb)
{
    __shared__ unsigned short sA[128][40];
    __shared__ unsigned short sB[128][40];
    int tid = threadIdx.x;
    int wave = tid >> 6, lane = tid & 63;
    int wm = (wave >> 1) * 64, wn = (wave & 1) * 64;
    int m0 = blockIdx.x * 128, n0 = blockIdx.y * 128;

    int r0 = tid >> 2;
    int c8 = (tid & 3) * 8;

    floatx4 acc[4][4];
#pragma unroll
    for (int i = 0; i < 4; i++)
#pragma unroll
        for (int j = 0; j < 4; j++) acc[i][j] = 0;

    int ml = lane & 15, kq = (lane >> 4) * 8;

    for (int k0 = 0; k0 < 384; k0 += 32) {
        short8 a0 = *(const short8*)(Ab + (size_t)(m0 + r0) * 384 + k0 + c8);
        short8 a1 = *(const short8*)(Ab + (size_t)(m0 + r0 + 64) * 384 + k0 + c8);
        short8 b0 = *(const short8*)(Bb + (size_t)(n0 + r0) * 384 + k0 + c8);
        short8 b1 = *(const short8*)(Bb + (size_t)(n0 + r0 + 64) * 384 + k0 + c8);

        __syncthreads();
        *(short8*)(&sA[r0][c8])      = a0;
        *(short8*)(&sA[r0 + 64][c8]) = a1;
        *(short8*)(&sB[r0][c8])      = b0;
        *(short8*)(&sB[r0 + 64][c8]) = b1;
        __syncthreads();

        short8 af[4], bf[4];
#pragma unroll
        for (int i = 0; i < 4; i++)
            af[i] = *(const short8*)(&sA[wm + i * 16 + ml][kq]);
#pragma unroll
        for (int j = 0; j < 4; j++)
            bf[j] = *(const short8*)(&sB[wn + j * 16 + ml][kq]);
#pragma unroll
        for (int i = 0; i < 4; i++)
#pragma unroll
            for (int j = 0; j < 4; j++)
                acc[i][j] = __builtin_amdgcn_mfma_f32_16x16x32_bf16(af[i], bf[j], acc[i][j], 0, 0, 0);
    }

    int cn = lane & 15, rq = (lane >> 4) * 4;
#pragma unroll
    for (int i = 0; i < 4; i++)
#pragma unroll
        for (int j = 0; j < 4; j++)
#pragma unroll
            for (int r = 0; r < 4; r++)
                Cb[(size_t)(m0 + wm + i * 16 + rq + r) * NHC + n0 + wn + j * 16 + cn] = f2b(acc[i][j][r]);
}

// ------------------------------------------------ node attention scores (+ Kh in extra block)
__global__ __launch_bounds__(256) void att_score_kernel(
    const unsigned short* __restrict__ h_bf,
    const float* __restrict__ att_src,
    const float* __restrict__ att_dst,
    const float* __restrict__ Wedge,
    const float* __restrict__ att_edge,
    float* __restrict__ a_src, float* __restrict__ a_dst,
    float* __restrict__ Kh)
{
    if (blockIdx.x == (N_NODES * 3) / 4) {   // extra block: edge_const work
        if (threadIdx.x < 192) {
            int hd = threadIdx.x >> 6, lane = threadIdx.x & 63;
            float s = 0.f;
#pragma unroll
            for (int q = 0; q < 6; q++) {
                int c = lane + q * 64;
                s += Wedge[hd * CDIM + c] * att_edge[hd * CDIM + c];
            }
#pragma unroll
            for (int off = 32; off; off >>= 1) s += __shfl_down(s, off, 64);
            if (lane == 0) Kh[hd] = s;
        }
        return;
    }
    int w = (blockIdx.x * 256 + threadIdx.x) >> 6;
    int lane = threadIdx.x & 63;
    int n = w / 3, hd = w % 3;
    const unsigned short* hrow = h_bf + (size_t)n * NHC + hd * CDIM;
    float s0 = 0.f, s1 = 0.f;
#pragma unroll
    for (int q = 0; q < 6; q++) {
        int c = lane + q * 64;
        float hv = b2f(hrow[c]);
        s0 += hv * att_src[hd * CDIM + c];
        s1 += hv * att_dst[hd * CDIM + c];
    }
#pragma unroll
    for (int off = 32; off; off >>= 1) {
        s0 += __shfl_down(s0, off, 64);
        s1 += __shfl_down(s1, off, 64);
    }
    if (lane == 0) { a_src[n * 3 + hd] = s0; a_dst[n * 3 + hd] = s1; }
}

__global__ __launch_bounds__(256) void edge_score_kernel(
    const int* __restrict__ edge_index,
    const float* __restrict__ edge_attr,
    const float* __restrict__ a_src, const float* __restrict__ a_dst,
    const float* __restrict__ Kh,
    float* __restrict__ a_raw, unsigned* __restrict__ amax_enc,
    int* __restrict__ deg)
{
    int tid = blockIdx.x * 256 + threadIdx.x;
    int hd = tid >> 16;
    int e = tid & (E_EDGES - 1);
    int src = edge_index[e];
    int dst = edge_index[E_EDGES + e];
    float a = a_src[src * 3 + hd] + a_dst[dst * 3 + hd] + edge_attr[e] * Kh[hd];
    a = a > 0.f ? a : 0.2f * a;
    a_raw[hd * E_EDGES + e] = a;
    atomicMax(&amax_enc[dst * 3 + hd], enc_f(a));
    if (hd == 0) atomicAdd(&deg[dst], 1);
}

// parallel exclusive scan of deg[8192] (single block, shfl_up wave scans)
__global__ __launch_bounds__(256) void scan_kernel(
    const int* __restrict__ deg, int* __restrict__ rowstart, int* __restrict__ cursor)
{
    __shared__ int wtot[4];
    int t = threadIdx.x;
    int lane = t & 63, wv = t >> 6;
    int l[32], s = 0;
#pragma unroll
    for (int i = 0; i < 32; i++) { l[i] = deg[t * 32 + i]; s += l[i]; }
    int sc = s;   // inclusive scan across wave
#pragma unroll
    for (int off = 1; off <= 32; off <<= 1) {
        int v = __shfl_up(sc, off, 64);
        if (lane >= off) sc += v;
    }
    if (lane == 63) wtot[wv] = sc;
    __syncthreads();
    int woff = 0;
#pragma unroll
    for (int w = 0; w < 4; w++) if (w < wv) woff += wtot[w];
    int b = woff + sc - s;   // exclusive start for this thread's 32 elems
#pragma unroll
    for (int i = 0; i < 32; i++) {
        rowstart[t * 32 + i] = b;
        cursor[t * 32 + i] = b;
        b += l[i];
    }
}

__global__ __launch_bounds__(256) void edge_exp_kernel(
    const int* __restrict__ edge_index,
    const float* __restrict__ a_raw, const unsigned* __restrict__ amax_enc,
    float* __restrict__ w_exp, float* __restrict__ denom,
    int* __restrict__ cursor, int* __restrict__ csr_e)
{
    int tid = blockIdx.x * 256 + threadIdx.x;
    int hd = tid >> 16;
    int e = tid & (E_EDGES - 1);
    int dst = edge_index[E_EDGES + e];
    float m = dec_f(amax_enc[dst * 3 + hd]);
    float w = expf(a_raw[hd * E_EDGES + e] - m);
    w_exp[hd * E_EDGES + e] = w;
    unsafeAtomicAdd(&denom[dst * 3 + hd], w);
    if (hd == 0) {
        int pos = atomicAdd(&cursor[dst], 1);
        csr_e[pos] = e;
    }
}

// CSR aggregation fused with head-mean+bias, predictor MLP, out_pred write.
__global__ __launch_bounds__(384) void aggregate_fused(
    const int* __restrict__ flag,
    const int* __restrict__ edge_index,
    const unsigned short* __restrict__ h_bf,
    const float* __restrict__ w_exp, const float* __restrict__ denom,
    const int* __restrict__ rowstart, const int* __restrict__ deg,
    const int* __restrict__ csr_e,
    const float* __restrict__ gat_bias,
    const float* __restrict__ Wp1, const float* __restrict__ bp1,
    const float* __restrict__ Wp3, const float* __restrict__ bp3,
    float* __restrict__ gmean,
    void* __restrict__ out_pred)
{
    int dst = blockIdx.x;
    int s = rowstart[dst], d = deg[dst];
    int tid = threadIdx.x;
    const float third = 1.f / 3.f;
    float inv0 = third / (denom[dst * 3 + 0] + 1e-16f);
    float inv1 = third / (denom[dst * 3 + 1] + 1e-16f);
    float inv2 = third / (denom[dst * 3 + 2] + 1e-16f);
    __shared__ int ssrc[64];
    __shared__ float sc0[64], sc1[64], sc2[64];
    __shared__ float gs[384];
    __shared__ float ps[12];
    float a = 0.f;
    for (int ch = 0; ch < d; ch += 64) {
        int m = d - ch; if (m > 64) m = 64;
        __syncthreads();
        if (tid < m) {
            int e = csr_e[s + ch + tid];
            ssrc[tid] = edge_index[e];
            sc0[tid] = w_exp[e] * inv0;
            sc1[tid] = w_exp[E_EDGES + e] * inv1;
            sc2[tid] = w_exp[2 * E_EDGES + e] * inv2;
        }
        __syncthreads();
        for (int i = 0; i < m; i++) {
            const unsigned short* hs = h_bf + (size_t)ssrc[i] * NHC;
            a += sc0[i] * b2f(hs[tid]) + sc1[i] * b2f(hs[tid + CDIM]) + sc2[i] * b2f(hs[tid + 2 * CDIM]);
        }
    }
    float g = a + gat_bias[tid];
    gmean[(size_t)dst * CDIM + tid] = g;
    gs[tid] = g;
    __syncthreads();

    int t = tid >> 5, c = tid & 31;
    float v = gs[t * 32 + c] * Wp1[c];
#pragma unroll
    for (int off = 16; off; off >>= 1) v += __shfl_down(v, off, 32);
    if (c == 0) { float p = v + bp1[0]; ps[t] = p > 0.f ? p : 0.f; }
    __syncthreads();

    if (tid < PRED_LEN) {
        float acc = bp3[tid];
#pragma unroll
        for (int tt = 0; tt < 12; tt++) acc += Wp3[tid * 12 + tt] * ps[tt];
        acc = acc > 0.f ? acc : 0.f;
        size_t oi = (size_t)dst * PRED_LEN + tid;
        if (*flag) ((__hip_bfloat16*)out_pred)[oi] = __float2bfloat16(acc);
        else       ((float*)out_pred)[oi] = acc;
    }
}

__global__ __launch_bounds__(384) void pool_kernel(
    const float* __restrict__ gmean,
    unsigned* __restrict__ pooled_enc)
{
    int b = blockIdx.x, ch = blockIdx.y;
    int tid = threadIdx.x;
    const float* base = gmean + ((size_t)b * 1024 + ch * 64) * CDIM + tid;
    float m = -3.4e38f;
    for (int i = 0; i < 64; i++)
        m = fmaxf(m, base[(size_t)i * CDIM]);
    atomicMax(&pooled_enc[b * CDIM + tid], enc_f(m));
}

__global__ __launch_bounds__(384) void cls_kernel(
    const int* __restrict__ flag,
    const unsigned* __restrict__ pooled_enc,
    const float* __restrict__ Wc1, const float* __restrict__ bc1,
    const float* __restrict__ Wc2, const float* __restrict__ bc2,
    void* __restrict__ out_base)
{
    int b = blockIdx.x, t = threadIdx.x;
    __shared__ float l1[32];
    if (t < 32) l1[t] = bc1[t];
    __syncthreads();
    float v = dec_f(pooled_enc[b * CDIM + t]);
#pragma unroll
    for (int i = 0; i < 32; i++) {
        float p = v * Wc1[i * CDIM + t];
#pragma unroll
        for (int off = 32; off; off >>= 1) p += __shfl_down(p, off, 64);
        if ((t & 63) == 0) atomicAdd(&l1[i], p);
    }
    __syncthreads();
    if (t == 0) {
        float l0 = bc2[0], l1v = bc2[1];
#pragma unroll
        for (int ii = 0; ii < 32; ii++) {
            l0  += Wc2[ii] * l1[ii];
            l1v += Wc2[32 + ii] * l1[ii];
        }
        float m = fmaxf(l0, l1v);
        float e0 = expf(l0 - m), e1 = expf(l1v - m);
        float s = e0 + e1;
        if (*flag) {
            __hip_bfloat16* ob = (__hip_bfloat16*)out_base;
            ob[OUT_LABEL_OFF + b * 2 + 0] = __float2bfloat16(e0 / s);
            ob[OUT_LABEL_OFF + b * 2 + 1] = __float2bfloat16(e1 / s);
        } else {
            float* of = (float*)out_base;
            of[OUT_LABEL_OFF + b * 2 + 0] = e0 / s;
            of[OUT_LABEL_OFF + b * 2 + 1] = e1 / s;
        }
    }
}

extern "C" void kernel_launch(void* const* d_in, const int* in_sizes, int n_in,
                              void* d_out, int out_size, void* d_ws, size_t ws_size,
                              hipStream_t stream) {
    float* W = (float*)d_ws;
    int* flag = (int*)(W + O_FLAG);
    const int* edge_index = (const int*)d_in[1];

    fill_detect<<<236, 256, 0, stream>>>(
        (const unsigned short*)d_in[5], flag, W);
    convert_all<<<(CONV_TOTAL + 255) / 256, 256, 0, stream>>>(
        flag,
        d_in[0], d_in[5], d_in[6], d_in[7], d_in[8],
        d_in[9], d_in[10], d_in[11], d_in[12], d_in[13],
        d_in[14], d_in[15], d_in[16], d_in[17], d_in[18],
        d_in[19], d_in[20], d_in[21], d_in[22], d_in[2],
        W, (unsigned short*)(W + O_WGATB));

    gru_kernel<<<N_NODES * 32 / 256, 256, 0, stream>>>(
        W + O_X, W + O_WIH, W + O_WHH, W + O_BIH, W + O_BHH,
        (unsigned short*)(W + O_GATB));
    gemm_mfma<<<dim3(N_NODES / 128, NHC / 128), 256, 0, stream>>>(
        (const unsigned short*)(W + O_GATB),
        (const unsigned short*)(W + O_WGATB),
        (unsigned short*)(W + O_HFEAT));
    att_score_kernel<<<(N_NODES * 3) / 4 + 1, 256, 0, stream>>>(
        (const unsigned short*)(W + O_HFEAT), W + O_ATTS, W + O_ATTD,
        W + O_WEDGE, W + O_ATTE,
        W + O_ASRC, W + O_ADST, W + O_KH);
    edge_score_kernel<<<3 * E_EDGES / 256, 256, 0, stream>>>(
        edge_index, W + O_EATTR, W + O_ASRC, W + O_ADST, W + O_KH,
        W + O_ARAW, (unsigned*)(W + O_AMAX), (int*)(W + O_DEG));
    scan_kernel<<<1, 256, 0, stream>>>(
        (const int*)(W + O_DEG), (int*)(W + O_ROWST), (int*)(W + O_CURS));
    edge_exp_kernel<<<3 * E_EDGES / 256, 256, 0, stream>>>(
        edge_index, W + O_ARAW, (const unsigned*)(W + O_AMAX),
        W + O_WEXP, W + O_DENOM, (int*)(W + O_CURS), (int*)(W + O_CSRE));
    aggregate_fused<<<N_NODES, 384, 0, stream>>>(
        flag, edge_index, (const unsigned short*)(W + O_HFEAT),
        W + O_WEXP, W + O_DENOM,
        (const int*)(W + O_ROWST), (const int*)(W + O_DEG),
        (const int*)(W + O_CSRE),
        W + O_GBIAS, W + O_WP1, W + O_BP1, W + O_WP3, W + O_BP3,
        W + O_GMEAN, d_out);
    pool_kernel<<<dim3(8, 16), 384, 0, stream>>>(
        W + O_GMEAN, (unsigned*)(W + O_POOLED));
    cls_kernel<<<8, 384, 0, stream>>>(
        flag, (const unsigned*)(W + O_POOLED),
        W + O_WC1, W + O_BC1, W + O_WC2, W + O_BC2, d_out);
}